// Round 4
// baseline (883.147 us; speedup 1.0000x reference)
//
#include <hip/hip_runtime.h>
#include <hip/hip_bf16.h>
#include <hip/hip_cooperative_groups.h>
#include <math.h>

namespace cg = cooperative_groups;

#define N_NODES 10000
#define MPAD 10112        // 158 * 64
#define N_EDGES 320000
#define IN_DIM 256
#define NH 4
#define EDIM 32
#define NT 8
#define SLOPE 0.2f

#define FBW (MPAD * IN_DIM / 8)   // 323584 featb items (8 bf16 each)
#define WTW (512 * 256)           // 131072 Wtb items
#define PREP_TOTAL (FBW + WTW + N_EDGES + 1024)
#define GEMM_TILES 1264           // 158 row-tiles x 8 col-tiles

typedef __attribute__((ext_vector_type(8))) short short8b;
typedef __attribute__((ext_vector_type(4))) float f32x4;

struct Params {
  const float* feat; const int* row; const int* col; const int* etype;
  const float* ew; const float* W; const float* table; const float* W_r;
  const float* a_l; const float* a_r; const float* a_e; const float* W_res;
  const float* b_res; float* out;
  ushort* featb; ushort* Wtb; ushort* emb_t; float* res; float* attp;
  int* srcp; float* hl; float* hr; float* he_type; int* cnt; int* off;
  int* cursor;
};

__device__ __forceinline__ float bf2f(ushort u) {
  return __uint_as_float(((unsigned)u) << 16);
}
__device__ __forceinline__ ushort f2bf(float f) {
  __hip_bfloat16 h = __float2bfloat16(f);
  return *(ushort*)&h;
}

// ---------------- prep item: featb | Wtb | hist | he_type ----------------
__device__ __forceinline__ void prep_item(const Params& p, int i) {
  if (i < FBW) {
    int idx = i * 8;
    int r = idx >> 8;
    int4 o = make_int4(0, 0, 0, 0);
    ushort* tp = (ushort*)&o;
    if (r < N_NODES) {
      float4 x = *(const float4*)&p.feat[idx];
      float4 y = *(const float4*)&p.feat[idx + 4];
      tp[0] = f2bf(x.x); tp[1] = f2bf(x.y); tp[2] = f2bf(x.z); tp[3] = f2bf(x.w);
      tp[4] = f2bf(y.x); tp[5] = f2bf(y.y); tp[6] = f2bf(y.z); tp[7] = f2bf(y.w);
    }
    *(int4*)&p.featb[idx] = o;
  } else if (i < FBW + WTW) {
    int j = i - FBW;
    int c = j >> 8, k = j & 255;
    float v = (c < 256) ? p.W[k * 256 + c] : p.W_res[k * 256 + (c - 256)];
    p.Wtb[c * 256 + k] = f2bf(v);
  } else if (i < FBW + WTW + N_EDGES) {
    int e = i - FBW - WTW;
    atomicAdd(&p.cnt[p.col[e]], 1);
  } else {
    int t2 = i - FBW - WTW - N_EDGES;  // 0..1023
    int t = t2 >> 7, h = (t2 >> 5) & 3, d = t2 & 31;
    float acc = 0.f;
    for (int q = 0; q < EDIM; ++q)
      acc += p.table[t * EDIM + q] * p.W_r[(t * EDIM + q) * (EDIM * NH) + h * EDIM + d];
    acc *= p.a_e[h * EDIM + d];
#pragma unroll
    for (int o = 16; o; o >>= 1) acc += __shfl_xor(acc, o, 32);
    if (d == 0) p.he_type[t * NH + h] = acc;
  }
}

// ---------------- per-wave MFMA GEMM tile (64 rows x 64 cols) ----------------
__device__ __forceinline__ void gemm_wave(const Params& p, int tile, int lane) {
  const int row0 = (tile >> 3) * 64;
  const int col0 = (tile & 7) * 64;
  const int lr = lane & 15;
  const int lk = (lane >> 4) * 8;
  f32x4 acc[4][4] = {};
  const ushort* Ab = p.featb + (size_t)(row0 + lr) * IN_DIM + lk;
  const ushort* Bb = p.Wtb + (size_t)(col0 + lr) * IN_DIM + lk;

#pragma unroll
  for (int ks = 0; ks < 8; ++ks) {
    short8b a[4], b[4];
#pragma unroll
    for (int m = 0; m < 4; ++m)
      a[m] = *(const short8b*)(Ab + (size_t)(m * 16) * IN_DIM + ks * 32);
#pragma unroll
    for (int n = 0; n < 4; ++n)
      b[n] = *(const short8b*)(Bb + (size_t)(n * 16) * IN_DIM + ks * 32);
#pragma unroll
    for (int m = 0; m < 4; ++m)
#pragma unroll
      for (int n = 0; n < 4; ++n)
        acc[m][n] = __builtin_amdgcn_mfma_f32_16x16x32_bf16(a[m], b[n], acc[m][n], 0, 0, 0);
  }

  const int rbase = row0 + (lane >> 4) * 4;
  if (col0 < 256) {
#pragma unroll
    for (int m = 0; m < 4; ++m)
#pragma unroll
      for (int n = 0; n < 4; ++n) {
        int c = col0 + n * 16 + lr;
        int d = c & 63, h = c >> 6;
#pragma unroll
        for (int j = 0; j < 4; ++j) {
          int r = rbase + m * 16 + j;
          if (r < N_NODES) p.emb_t[(size_t)r * 256 + d * 4 + h] = f2bf(acc[m][n][j]);
        }
      }
    const int h = col0 >> 6;
    float al[4], ar[4];
#pragma unroll
    for (int n = 0; n < 4; ++n) {
      al[n] = p.a_l[h * 64 + n * 16 + lr];
      ar[n] = p.a_r[h * 64 + n * 16 + lr];
    }
#pragma unroll
    for (int m = 0; m < 4; ++m)
#pragma unroll
      for (int j = 0; j < 4; ++j) {
        float pl = acc[m][0][j] * al[0] + acc[m][1][j] * al[1] +
                   acc[m][2][j] * al[2] + acc[m][3][j] * al[3];
        float pr = acc[m][0][j] * ar[0] + acc[m][1][j] * ar[1] +
                   acc[m][2][j] * ar[2] + acc[m][3][j] * ar[3];
#pragma unroll
        for (int o = 1; o < 16; o <<= 1) {
          pl += __shfl_xor(pl, o);
          pr += __shfl_xor(pr, o);
        }
        int r = rbase + m * 16 + j;
        if (lr == 0 && r < N_NODES) {
          p.hl[r * 4 + h] = pl;
          p.hr[r * 4 + h] = pr;
        }
      }
  } else {
#pragma unroll
    for (int m = 0; m < 4; ++m)
#pragma unroll
      for (int n = 0; n < 4; ++n) {
        int c = (col0 - 256) + n * 16 + lr;
        float br = p.b_res[c];
#pragma unroll
        for (int j = 0; j < 4; ++j) {
          int r = rbase + m * 16 + j;
          if (r < N_NODES) p.res[(size_t)r * 256 + c] = acc[m][n][j] + br;
        }
      }
  }
}

// ---------------- 256-thread block scan of cnt -> off, cursor ----------------
__device__ void scan_block(const int* __restrict__ cnt, int* __restrict__ off,
                           int* __restrict__ cursor) {
  __shared__ int wsum[5];
  int tid = threadIdx.x, wid = tid >> 6, lane = tid & 63;
  int carry = 0;
  for (int chunk = 0; chunk < 40; ++chunk) {
    int i = chunk * 256 + tid;
    int v = (i < N_NODES) ? cnt[i] : 0;
    int x = v;
#pragma unroll
    for (int d = 1; d < 64; d <<= 1) {
      int t = __shfl_up(x, d);
      if (lane >= d) x += t;
    }
    if (lane == 63) wsum[wid] = x;
    __syncthreads();
    if (tid == 0) {
      int s = 0;
#pragma unroll
      for (int j = 0; j < 4; ++j) { int t = wsum[j]; wsum[j] = s; s += t; }
      wsum[4] = s;
    }
    __syncthreads();
    if (i < N_NODES) {
      int ex = carry + wsum[wid] + x - v;
      off[i] = ex;
      cursor[i] = ex;
    }
    carry += wsum[4];
    __syncthreads();
  }
  if (tid == 0) off[N_NODES] = carry;
}

// ---------------- fused attention + CSR scatter for one edge ----------------
__device__ __forceinline__ void scatter_edge(const Params& p, int e) {
  int r = p.row[e], c = p.col[e], t = p.etype[e];
  float w = p.ew[e];
  float4 L = *(const float4*)&p.hl[r * 4];
  float4 R = *(const float4*)&p.hr[c * 4];
  float4 Hh = *(const float4*)&p.he_type[t * 4];
  float x[4] = {L.x + R.x + Hh.x, L.y + R.y + Hh.y, L.z + R.z + Hh.z, L.w + R.w + Hh.w};
  float4 o;
  float* op = &o.x;
#pragma unroll
  for (int h = 0; h < 4; ++h) {
    float v = x[h];
    v = v >= 0.f ? v : SLOPE * v;
    op[h] = w / (1.f + expf(-v));
  }
  int pp = atomicAdd(&p.cursor[c], 1);
  p.srcp[pp] = r;
  *(float4*)&p.attp[(size_t)pp * 4] = o;
}

// ---------------- aggregation for one dst node (one wave) ----------------
__device__ __forceinline__ void agg_node(const Params& p, int n, int lane) {
  float acc0 = 0.f, acc1 = 0.f, acc2 = 0.f, acc3 = 0.f;
  int s = p.off[n], e = p.off[n + 1];
  for (int base = s; base < e; base += 64) {
    int cnt = min(64, e - base);
    int src = 0;
    float ax = 0.f, ay = 0.f, az = 0.f, aw = 0.f;
    if (lane < cnt) {
      src = p.srcp[base + lane];
      float4 a = *(const float4*)&p.attp[(size_t)(base + lane) * 4];
      ax = a.x; ay = a.y; az = a.z; aw = a.w;
    }
#pragma unroll 4
    for (int j = 0; j < cnt; ++j) {
      int sj = __shfl(src, j);
      float bx = __shfl(ax, j), by = __shfl(ay, j);
      float bz = __shfl(az, j), bw = __shfl(aw, j);
      ushort4 v = *(const ushort4*)&p.emb_t[(size_t)sj * 256 + lane * 4];
      acc0 = fmaf(bf2f(v.x), bx, acc0);
      acc1 = fmaf(bf2f(v.y), by, acc1);
      acc2 = fmaf(bf2f(v.z), bz, acc2);
      acc3 = fmaf(bf2f(v.w), bw, acc3);
    }
  }
  float4 r4 = *(const float4*)&p.res[(size_t)n * 256 + lane * 4];
  float v0 = acc0 + r4.x, v1 = acc1 + r4.y, v2 = acc2 + r4.z, v3 = acc3 + r4.w;
  float4 o;
  o.x = v0 > 0.f ? v0 : expm1f(v0);
  o.y = v1 > 0.f ? v1 : expm1f(v1);
  o.z = v2 > 0.f ? v2 : expm1f(v2);
  o.w = v3 > 0.f ? v3 : expm1f(v3);
  *(float4*)&p.out[(size_t)n * 256 + lane * 4] = o;
}

// ---------------- cooperative mega-kernel: all phases, one dispatch ----------------
__global__ __launch_bounds__(256, 4) void mega_kernel(Params p) {
  cg::grid_group grid = cg::this_grid();
  const int gtid = blockIdx.x * 256 + threadIdx.x;
  const int gsz = gridDim.x * 256;
  const int lane = threadIdx.x & 63;

  // phase 0: zero histogram
  for (int i = gtid; i <= N_NODES; i += gsz) p.cnt[i] = 0;
  __threadfence();
  grid.sync();

  // phase 1: featb + Wtb + histogram + he_type
  for (int i = gtid; i < PREP_TOTAL; i += gsz) prep_item(p, i);
  __threadfence();
  grid.sync();

  // phase 2: GEMM on waves >= 4, scan on block 0 (concurrent)
  if (blockIdx.x == 0) {
    scan_block(p.cnt, p.off, p.cursor);
  } else {
    int t = (gtid >> 6) - 4;
    if (t < GEMM_TILES) gemm_wave(p, t, lane);
  }
  __threadfence();
  grid.sync();

  // phase 3: attention + CSR scatter
  for (int e = gtid; e < N_EDGES; e += gsz) scatter_edge(p, e);
  __threadfence();
  grid.sync();

  // phase 4: aggregation + residual + ELU
  const int nw = gsz >> 6;
  for (int n = gtid >> 6; n < N_NODES; n += nw) agg_node(p, n, lane);
}

// ---------------- fallback kernels (same device code, split dispatches) ------
__global__ void prep_kernel_fb(Params p) {
  int i = blockIdx.x * 256 + threadIdx.x;
  if (i < PREP_TOTAL) prep_item(p, i);
}
__global__ __launch_bounds__(128) void gemm_kernel_fb(Params p) {
  int wave = threadIdx.x >> 6, lane = threadIdx.x & 63;
  int tile = ((blockIdx.x * 2 + wave) << 3) | blockIdx.y;
  gemm_wave(p, tile, lane);
}
__global__ void scan_kernel_fb(Params p) { scan_block(p.cnt, p.off, p.cursor); }
__global__ void scatter_kernel_fb(Params p) {
  int e = blockIdx.x * 256 + threadIdx.x;
  if (e < N_EDGES) scatter_edge(p, e);
}
__global__ __launch_bounds__(256) void agg_kernel_fb(Params p) {
  int n = blockIdx.x * 4 + (threadIdx.x >> 6);
  if (n < N_NODES) agg_node(p, n, threadIdx.x & 63);
}

extern "C" void kernel_launch(void* const* d_in, const int* in_sizes, int n_in,
                              void* d_out, int out_size, void* d_ws, size_t ws_size,
                              hipStream_t stream) {
  char* w = (char*)d_ws;
  auto alloc = [&](size_t bytes) {
    char* pp = w;
    w += (bytes + 255) & ~(size_t)255;
    return pp;
  };

  Params p;
  p.feat = (const float*)d_in[0];
  p.ew = (const float*)d_in[1];
  p.row = (const int*)d_in[2];
  p.col = (const int*)d_in[3];
  p.etype = (const int*)d_in[4];
  p.W = (const float*)d_in[5];
  p.table = (const float*)d_in[6];
  p.W_r = (const float*)d_in[7];
  p.a_l = (const float*)d_in[8];
  p.a_r = (const float*)d_in[9];
  p.a_e = (const float*)d_in[10];
  p.W_res = (const float*)d_in[11];
  p.b_res = (const float*)d_in[12];
  p.out = (float*)d_out;

  p.featb = (ushort*)alloc((size_t)MPAD * IN_DIM * 2);
  p.Wtb = (ushort*)alloc((size_t)512 * 256 * 2);
  p.emb_t = (ushort*)alloc((size_t)N_NODES * 256 * 2);
  p.res = (float*)alloc((size_t)N_NODES * 256 * 4);
  p.attp = (float*)alloc((size_t)N_EDGES * NH * 4);
  p.srcp = (int*)alloc((size_t)N_EDGES * 4);
  p.hl = (float*)alloc((size_t)N_NODES * NH * 4);
  p.hr = (float*)alloc((size_t)N_NODES * NH * 4);
  p.he_type = (float*)alloc(NT * NH * 4);
  p.cnt = (int*)alloc((size_t)(N_NODES + 1) * 4);
  p.off = (int*)alloc((size_t)(N_NODES + 1) * 4);
  p.cursor = (int*)alloc((size_t)N_NODES * 4);

  void* args[] = {(void*)&p};
  hipError_t err = hipLaunchCooperativeKernel((const void*)mega_kernel, dim3(1024),
                                              dim3(256), args, 0, stream);
  if (err != hipSuccess) {
    (void)hipGetLastError();  // clear error state, use split-dispatch fallback
    hipMemsetAsync(p.cnt, 0, (size_t)(N_NODES + 1) * 4, stream);
    prep_kernel_fb<<<PREP_TOTAL / 256, 256, 0, stream>>>(p);
    gemm_kernel_fb<<<dim3(79, 8), 128, 0, stream>>>(p);
    scan_kernel_fb<<<1, 256, 0, stream>>>(p);
    scatter_kernel_fb<<<(N_EDGES + 255) / 256, 256, 0, stream>>>(p);
    agg_kernel_fb<<<N_NODES / 4 + 1, 256, 0, stream>>>(p);
  }
}

// Round 5
// 108.769 us; speedup vs baseline: 8.1195x; 8.1195x over previous
//
#include <hip/hip_runtime.h>
#include <hip/hip_bf16.h>
#include <math.h>

#define N_NODES 10000
#define MPAD 10112        // 158 * 64
#define N_EDGES 320000
#define IN_DIM 256
#define NH 4
#define EDIM 32
#define NT 8
#define SLOPE 0.2f
#define CAP 96            // bucket capacity per dst node (max degree ~56 for Poisson(32))

#define FBW (MPAD * IN_DIM / 8)   // featb items (8 bf16 each)
#define WTW (512 * 256)           // Wtb items
#define ZCNT (N_NODES + 1)
#define PREP_TOTAL (FBW + WTW + 1024 + ZCNT)

typedef __attribute__((ext_vector_type(8))) short short8b;
typedef __attribute__((ext_vector_type(4))) float f32x4;

__device__ __forceinline__ float bf2f(ushort u) {
  return __uint_as_float(((unsigned)u) << 16);
}
__device__ __forceinline__ ushort f2bf(float f) {
  __hip_bfloat16 h = __float2bfloat16(f);
  return *(ushort*)&h;
}

// ---------------- prep: featb + Wtb + he_type + zero cnt ----------------
__global__ void prep_kernel(const float* __restrict__ feat,
                            const float* __restrict__ W,
                            const float* __restrict__ W_res,
                            const float* __restrict__ table,
                            const float* __restrict__ W_r,
                            const float* __restrict__ a_e,
                            ushort* __restrict__ featb,
                            ushort* __restrict__ Wtb,
                            float* __restrict__ he_type,
                            int* __restrict__ cnt) {
  int i = blockIdx.x * 256 + threadIdx.x;
  if (i < FBW) {
    int idx = i * 8;
    int r = idx >> 8;
    int4 o = make_int4(0, 0, 0, 0);
    ushort* tp = (ushort*)&o;
    if (r < N_NODES) {
      float4 x = *(const float4*)&feat[idx];
      float4 y = *(const float4*)&feat[idx + 4];
      tp[0] = f2bf(x.x); tp[1] = f2bf(x.y); tp[2] = f2bf(x.z); tp[3] = f2bf(x.w);
      tp[4] = f2bf(y.x); tp[5] = f2bf(y.y); tp[6] = f2bf(y.z); tp[7] = f2bf(y.w);
    }
    *(int4*)&featb[idx] = o;
  } else if (i < FBW + WTW) {
    int j = i - FBW;
    int c = j >> 8, k = j & 255;
    float v = (c < 256) ? W[k * 256 + c] : W_res[k * 256 + (c - 256)];
    Wtb[c * 256 + k] = f2bf(v);
  } else if (i < FBW + WTW + 1024) {
    int t2 = i - FBW - WTW;  // 0..1023
    int t = t2 >> 7, h = (t2 >> 5) & 3, d = t2 & 31;
    float acc = 0.f;
    for (int q = 0; q < EDIM; ++q)
      acc += table[t * EDIM + q] * W_r[(t * EDIM + q) * (EDIM * NH) + h * EDIM + d];
    acc *= a_e[h * EDIM + d];
#pragma unroll
    for (int o = 16; o; o >>= 1) acc += __shfl_xor(acc, o, 32);
    if (d == 0) he_type[t * NH + h] = acc;
  } else if (i < PREP_TOTAL) {
    cnt[i - FBW - WTW - 1024] = 0;
  }
}

// ---------------- MFMA GEMM + hl/hr epilogue; emb -> 2 head-pair planes ----------------
// C[M,512] = featb @ Wtb^T ; cols<256 -> emb01/emb23 (bf16 planes) + hl/hr,
// cols>=256 -> resb (bf16, out layout) + b_res.
__global__ __launch_bounds__(128) void gemm_kernel(
    const ushort* __restrict__ featb, const ushort* __restrict__ Wtb,
    const float* __restrict__ b_res,
    const float* __restrict__ a_l, const float* __restrict__ a_r,
    ushort* __restrict__ emb01, ushort* __restrict__ emb23,
    ushort* __restrict__ resb, float* __restrict__ hl, float* __restrict__ hr) {
  const int wave = threadIdx.x >> 6, lane = threadIdx.x & 63;
  const int row0 = (blockIdx.x * 2 + wave) * 64;
  const int col0 = blockIdx.y * 64;
  const int lr = lane & 15;
  const int lk = (lane >> 4) * 8;
  f32x4 acc[4][4] = {};
  const ushort* Ab = featb + (size_t)(row0 + lr) * IN_DIM + lk;
  const ushort* Bb = Wtb + (size_t)(col0 + lr) * IN_DIM + lk;

#pragma unroll
  for (int ks = 0; ks < 8; ++ks) {
    short8b a[4], b[4];
#pragma unroll
    for (int m = 0; m < 4; ++m)
      a[m] = *(const short8b*)(Ab + (size_t)(m * 16) * IN_DIM + ks * 32);
#pragma unroll
    for (int n = 0; n < 4; ++n)
      b[n] = *(const short8b*)(Bb + (size_t)(n * 16) * IN_DIM + ks * 32);
#pragma unroll
    for (int m = 0; m < 4; ++m)
#pragma unroll
      for (int n = 0; n < 4; ++n)
        acc[m][n] = __builtin_amdgcn_mfma_f32_16x16x32_bf16(a[m], b[n], acc[m][n], 0, 0, 0);
  }

  const int rbase = row0 + (lane >> 4) * 4;
  if (col0 < 256) {
    const int h = col0 >> 6;           // one head per 64-col block
    ushort* plane = (h < 2) ? emb01 : emb23;
    const int hb = h & 1;
#pragma unroll
    for (int m = 0; m < 4; ++m)
#pragma unroll
      for (int n = 0; n < 4; ++n) {
        int d = (col0 + n * 16 + lr) & 63;
#pragma unroll
        for (int j = 0; j < 4; ++j) {
          int r = rbase + m * 16 + j;
          if (r < N_NODES)
            plane[((size_t)r * 64 + d) * 2 + hb] = f2bf(acc[m][n][j]);
        }
      }
    float al[4], ar[4];
#pragma unroll
    for (int n = 0; n < 4; ++n) {
      al[n] = a_l[h * 64 + n * 16 + lr];
      ar[n] = a_r[h * 64 + n * 16 + lr];
    }
#pragma unroll
    for (int m = 0; m < 4; ++m)
#pragma unroll
      for (int j = 0; j < 4; ++j) {
        float pl = acc[m][0][j] * al[0] + acc[m][1][j] * al[1] +
                   acc[m][2][j] * al[2] + acc[m][3][j] * al[3];
        float pr = acc[m][0][j] * ar[0] + acc[m][1][j] * ar[1] +
                   acc[m][2][j] * ar[2] + acc[m][3][j] * ar[3];
#pragma unroll
        for (int o = 1; o < 16; o <<= 1) {
          pl += __shfl_xor(pl, o);
          pr += __shfl_xor(pr, o);
        }
        int r = rbase + m * 16 + j;
        if (lr == 0 && r < N_NODES) {
          hl[r * 4 + h] = pl;
          hr[r * 4 + h] = pr;
        }
      }
  } else {
#pragma unroll
    for (int m = 0; m < 4; ++m)
#pragma unroll
      for (int n = 0; n < 4; ++n) {
        int c = (col0 - 256) + n * 16 + lr;
        float br = b_res[c];
#pragma unroll
        for (int j = 0; j < 4; ++j) {
          int r = rbase + m * 16 + j;
          if (r < N_NODES) resb[(size_t)r * 256 + c] = f2bf(acc[m][n][j] + br);
        }
      }
  }
}

// ---------------- attention + bucket scatter ----------------
__global__ void scatter_kernel(const int* __restrict__ row,
                               const int* __restrict__ colv,
                               const int* __restrict__ et,
                               const float* __restrict__ ew,
                               const float* __restrict__ hl,
                               const float* __restrict__ hr,
                               const float* __restrict__ he_type,
                               int* cnt, int* __restrict__ srcb,
                               ushort* __restrict__ attb) {
  int e = blockIdx.x * 256 + threadIdx.x;
  if (e >= N_EDGES) return;
  int r = row[e], c = colv[e], t = et[e];
  float w = ew[e];
  float4 L = *(const float4*)&hl[r * 4];
  float4 R = *(const float4*)&hr[c * 4];
  float4 Hh = *(const float4*)&he_type[t * 4];
  float x[4] = {L.x + R.x + Hh.x, L.y + R.y + Hh.y, L.z + R.z + Hh.z, L.w + R.w + Hh.w};
  ushort4 ab;
  ushort* ap = (ushort*)&ab;
#pragma unroll
  for (int h = 0; h < 4; ++h) {
    float v = x[h];
    v = v >= 0.f ? v : SLOPE * v;
    ap[h] = f2bf(w / (1.f + expf(-v)));
  }
  int s = atomicAdd(&cnt[c], 1);
  if (s < CAP) {
    srcb[(size_t)c * CAP + s] = r;
    *(ushort4*)&attb[((size_t)c * CAP + s) * 4] = ab;
  }
}

// ---------------- aggregation pass P (heads 2P,2P+1): wave per dst node ----------------
template <int P>
__global__ __launch_bounds__(256) void agg_kernel(
    const int* __restrict__ cnt, const int* __restrict__ srcb,
    const ushort* __restrict__ attb, const ushort* __restrict__ emb_p,
    const ushort* __restrict__ resb, float* __restrict__ out) {
  int n = blockIdx.x * 4 + (threadIdx.x >> 6);
  int lane = threadIdx.x & 63;
  float acc0 = 0.f, acc1 = 0.f;
  int e = min(cnt[n], CAP);
  for (int base = 0; base < e; base += 64) {
    int c = min(64, e - base);
    int src = 0;
    float a0 = 0.f, a1 = 0.f;
    if (lane < c) {
      src = srcb[(size_t)n * CAP + base + lane];
      ushort2 av = *(const ushort2*)&attb[((size_t)n * CAP + base + lane) * 4 + P * 2];
      a0 = bf2f(av.x);
      a1 = bf2f(av.y);
    }
#pragma unroll 4
    for (int j = 0; j < c; ++j) {
      int sj = __shfl(src, j);
      float b0 = __shfl(a0, j), b1 = __shfl(a1, j);
      ushort2 v = *(const ushort2*)&emb_p[((size_t)sj * 64 + lane) * 2];
      acc0 = fmaf(bf2f(v.x), b0, acc0);
      acc1 = fmaf(bf2f(v.y), b1, acc1);
    }
  }
  ushort2 r2 = *(const ushort2*)&resb[(size_t)n * 256 + lane * 4 + P * 2];
  float v0 = acc0 + bf2f(r2.x), v1 = acc1 + bf2f(r2.y);
  float2 o;
  o.x = v0 > 0.f ? v0 : expm1f(v0);
  o.y = v1 > 0.f ? v1 : expm1f(v1);
  *(float2*)&out[(size_t)n * 256 + lane * 4 + P * 2] = o;
}

extern "C" void kernel_launch(void* const* d_in, const int* in_sizes, int n_in,
                              void* d_out, int out_size, void* d_ws, size_t ws_size,
                              hipStream_t stream) {
  const float* feat = (const float*)d_in[0];
  const float* ew = (const float*)d_in[1];
  const int* row = (const int*)d_in[2];
  const int* col = (const int*)d_in[3];
  const int* etype = (const int*)d_in[4];
  const float* W = (const float*)d_in[5];
  const float* table = (const float*)d_in[6];
  const float* W_r = (const float*)d_in[7];
  const float* a_l = (const float*)d_in[8];
  const float* a_r = (const float*)d_in[9];
  const float* a_e = (const float*)d_in[10];
  const float* W_res = (const float*)d_in[11];
  const float* b_res = (const float*)d_in[12];
  float* out = (float*)d_out;

  char* w = (char*)d_ws;
  auto alloc = [&](size_t bytes) {
    char* pp = w;
    w += (bytes + 255) & ~(size_t)255;
    return pp;
  };
  ushort* featb = (ushort*)alloc((size_t)MPAD * IN_DIM * 2);
  ushort* Wtb = (ushort*)alloc((size_t)512 * 256 * 2);
  ushort* emb01 = (ushort*)alloc((size_t)N_NODES * 128 * 2);
  ushort* emb23 = (ushort*)alloc((size_t)N_NODES * 128 * 2);
  ushort* resb = (ushort*)alloc((size_t)N_NODES * 256 * 2);
  int* srcb = (int*)alloc((size_t)N_NODES * CAP * 4);
  ushort* attb = (ushort*)alloc((size_t)N_NODES * CAP * 4 * 2);
  float* hl = (float*)alloc((size_t)N_NODES * NH * 4);
  float* hr = (float*)alloc((size_t)N_NODES * NH * 4);
  float* he_type = (float*)alloc(NT * NH * 4);
  int* cnt = (int*)alloc((size_t)(N_NODES + 1) * 4);

  prep_kernel<<<(PREP_TOTAL + 255) / 256, 256, 0, stream>>>(
      feat, W, W_res, table, W_r, a_e, featb, Wtb, he_type, cnt);
  gemm_kernel<<<dim3(79, 8), 128, 0, stream>>>(featb, Wtb, b_res, a_l, a_r,
                                               emb01, emb23, resb, hl, hr);
  scatter_kernel<<<(N_EDGES + 255) / 256, 256, 0, stream>>>(
      row, col, etype, ew, hl, hr, he_type, cnt, srcb, attb);
  agg_kernel<0><<<N_NODES / 4, 256, 0, stream>>>(cnt, srcb, attb, emb01, resb, out);
  agg_kernel<1><<<N_NODES / 4, 256, 0, stream>>>(cnt, srcb, attb, emb23, resb, out);
}

// Round 6
// 104.121 us; speedup vs baseline: 8.4820x; 1.0446x over previous
//
#include <hip/hip_runtime.h>
#include <hip/hip_bf16.h>
#include <math.h>

#define N_NODES 10000
#define MPAD 10112        // 316 * 32
#define N_EDGES 320000
#define IN_DIM 256
#define NH 4
#define EDIM 32
#define NT 8
#define SLOPE 0.2f
#define CAP 96            // bucket capacity per dst (Poisson(32): P(deg>96) ~ 1e-18)

#define WTW (512 * 256)           // Wtb items
#define ZCNT (N_NODES + 1)
#define PREP_TOTAL (WTW + 1024 + ZCNT)

typedef __attribute__((ext_vector_type(8))) short short8b;
typedef __attribute__((ext_vector_type(4))) float f32x4;

__device__ __forceinline__ float bf2f(ushort u) {
  return __uint_as_float(((unsigned)u) << 16);
}
__device__ __forceinline__ ushort f2bf(float f) {
  __hip_bfloat16 h = __float2bfloat16(f);
  return *(ushort*)&h;
}
__device__ __forceinline__ unsigned pk2(float a, float b) {
  return (unsigned)f2bf(a) | ((unsigned)f2bf(b) << 16);
}

// ---------------- prep: Wtb + he_type + zero cnt (small) ----------------
__global__ void prep_kernel(const float* __restrict__ W,
                            const float* __restrict__ W_res,
                            const float* __restrict__ table,
                            const float* __restrict__ W_r,
                            const float* __restrict__ a_e,
                            ushort* __restrict__ Wtb,
                            float* __restrict__ he_type,
                            int* __restrict__ cnt) {
  int i = blockIdx.x * 256 + threadIdx.x;
  if (i < WTW) {
    int c = i >> 8, k = i & 255;
    float v = (c < 256) ? W[k * 256 + c] : W_res[k * 256 + (c - 256)];
    Wtb[c * 256 + k] = f2bf(v);
  } else if (i < WTW + 1024) {
    int t2 = i - WTW;  // 0..1023 (block-aligned: WTW % 256 == 0)
    int t = t2 >> 7, h = (t2 >> 5) & 3, d = t2 & 31;
    float acc = 0.f;
    for (int q = 0; q < EDIM; ++q)
      acc += table[t * EDIM + q] * W_r[(t * EDIM + q) * (EDIM * NH) + h * EDIM + d];
    acc *= a_e[h * EDIM + d];
#pragma unroll
    for (int o = 16; o; o >>= 1) acc += __shfl_xor(acc, o, 32);
    if (d == 0) he_type[t * NH + h] = acc;
  } else if (i < PREP_TOTAL) {
    cnt[i - WTW - 1024] = 0;
  }
}

// ---------------- fused convert+GEMM: 32 rows x 512 cols per block, 8 waves ----------
// LDS-staged bf16 A tile (XOR-swizzled); B from global (L2-hot Wtb).
// cols<256 -> emb01/emb23 planes + hl/hr ; cols>=256 -> resb (bf16) + b_res.
__global__ __launch_bounds__(512) void gemm_kernel(
    const float* __restrict__ feat, const ushort* __restrict__ Wtb,
    const float* __restrict__ b_res,
    const float* __restrict__ a_l, const float* __restrict__ a_r,
    ushort* __restrict__ emb01, ushort* __restrict__ emb23,
    ushort* __restrict__ resb, float* __restrict__ hl, float* __restrict__ hr) {
  __shared__ ushort As[32 * 256];  // 16 KB, [row][k] with 16B-chunk XOR swizzle
  const int tid = threadIdx.x;
  const int rowbase = blockIdx.x * 32;

  // stage: 32 rows x 256 k fp32 -> bf16 LDS (coalesced float4 loads)
#pragma unroll
  for (int i = 0; i < 2; ++i) {
    int c = tid + i * 512;           // chunk id: 1024 chunks of 16B
    int rowl = c >> 5, slot = c & 31;
    int gr = rowbase + rowl;
    uint4 pk = make_uint4(0, 0, 0, 0);
    if (gr < N_NODES) {
      float4 x = *(const float4*)&feat[(size_t)gr * 256 + slot * 8];
      float4 y = *(const float4*)&feat[(size_t)gr * 256 + slot * 8 + 4];
      pk.x = pk2(x.x, x.y); pk.y = pk2(x.z, x.w);
      pk.z = pk2(y.x, y.y); pk.w = pk2(y.z, y.w);
    }
    int idx = rowl * 256 + (((slot * 16) ^ ((rowl & 7) << 4)) >> 1);
    *(uint4*)&As[idx] = pk;
  }
  __syncthreads();

  const int wave = tid >> 6, lane = tid & 63;
  const int col0 = wave * 64;
  const int lr = lane & 15;
  const int lkq = lane >> 4;        // k-quarter
  f32x4 acc[2][4] = {};
  const ushort* Bb = Wtb + (size_t)(col0 + lr) * 256 + lkq * 8;

#pragma unroll
  for (int ks = 0; ks < 8; ++ks) {
    short8b a[2], b[4];
#pragma unroll
    for (int m = 0; m < 2; ++m) {
      int rowl = m * 16 + lr;
      int kb = ks * 64 + lkq * 16;  // byte offset in row
      int idx = rowl * 256 + ((kb ^ ((rowl & 7) << 4)) >> 1);
      a[m] = *(const short8b*)&As[idx];
    }
#pragma unroll
    for (int n = 0; n < 4; ++n)
      b[n] = *(const short8b*)(Bb + (size_t)(n * 16) * 256 + ks * 32);
#pragma unroll
    for (int m = 0; m < 2; ++m)
#pragma unroll
      for (int n = 0; n < 4; ++n)
        acc[m][n] = __builtin_amdgcn_mfma_f32_16x16x32_bf16(a[m], b[n], acc[m][n], 0, 0, 0);
  }

  const int rbase = rowbase + lkq * 4;
  if (col0 < 256) {
    const int h = col0 >> 6;         // head = wave (0..3)
    ushort* plane = (h < 2) ? emb01 : emb23;
    const int hb = h & 1;
#pragma unroll
    for (int m = 0; m < 2; ++m)
#pragma unroll
      for (int n = 0; n < 4; ++n) {
        int d = (n * 16 + lr) & 63;
#pragma unroll
        for (int j = 0; j < 4; ++j) {
          int r = rbase + m * 16 + j;
          if (r < N_NODES)
            plane[((size_t)r * 64 + d) * 2 + hb] = f2bf(acc[m][n][j]);
        }
      }
    float al[4], ar[4];
#pragma unroll
    for (int n = 0; n < 4; ++n) {
      al[n] = a_l[h * 64 + n * 16 + lr];
      ar[n] = a_r[h * 64 + n * 16 + lr];
    }
#pragma unroll
    for (int m = 0; m < 2; ++m)
#pragma unroll
      for (int j = 0; j < 4; ++j) {
        float pl = acc[m][0][j] * al[0] + acc[m][1][j] * al[1] +
                   acc[m][2][j] * al[2] + acc[m][3][j] * al[3];
        float pr = acc[m][0][j] * ar[0] + acc[m][1][j] * ar[1] +
                   acc[m][2][j] * ar[2] + acc[m][3][j] * ar[3];
#pragma unroll
        for (int o = 1; o < 16; o <<= 1) {
          pl += __shfl_xor(pl, o);
          pr += __shfl_xor(pr, o);
        }
        int r = rbase + m * 16 + j;
        if (lr == 0 && r < N_NODES) {
          hl[r * 4 + h] = pl;
          hr[r * 4 + h] = pr;
        }
      }
  } else {
#pragma unroll
    for (int m = 0; m < 2; ++m)
#pragma unroll
      for (int n = 0; n < 4; ++n) {
        int c = (col0 - 256) + n * 16 + lr;
        float br = b_res[c];
#pragma unroll
        for (int j = 0; j < 4; ++j) {
          int r = rbase + m * 16 + j;
          if (r < N_NODES) resb[(size_t)r * 256 + c] = f2bf(acc[m][n][j] + br);
        }
      }
  }
}

// ---------------- attention + bucket scatter ----------------
__global__ void scatter_kernel(const int* __restrict__ row,
                               const int* __restrict__ colv,
                               const int* __restrict__ et,
                               const float* __restrict__ ew,
                               const float* __restrict__ hl,
                               const float* __restrict__ hr,
                               const float* __restrict__ he_type,
                               int* cnt, ushort* __restrict__ srcb,
                               ushort* __restrict__ attb) {
  int e = blockIdx.x * 256 + threadIdx.x;
  if (e >= N_EDGES) return;
  int r = row[e], c = colv[e], t = et[e];
  float w = ew[e];
  float4 L = *(const float4*)&hl[r * 4];
  float4 R = *(const float4*)&hr[c * 4];
  float4 Hh = *(const float4*)&he_type[t * 4];
  float x[4] = {L.x + R.x + Hh.x, L.y + R.y + Hh.y, L.z + R.z + Hh.z, L.w + R.w + Hh.w};
  ushort4 ab;
  ushort* ap = (ushort*)&ab;
#pragma unroll
  for (int h = 0; h < 4; ++h) {
    float v = x[h];
    v = v >= 0.f ? v : SLOPE * v;
    ap[h] = f2bf(w / (1.f + expf(-v)));
  }
  int s = atomicAdd(&cnt[c], 1);
  if (s < CAP) {
    srcb[(size_t)c * CAP + s] = (ushort)r;
    *(ushort4*)&attb[((size_t)c * CAP + s) * 4] = ab;
  }
}

// ---------------- aggregation: wave per dst node, plane = blockIdx.y ----------------
__global__ __launch_bounds__(256) void agg_kernel(
    const int* __restrict__ cnt, const ushort* __restrict__ srcb,
    const ushort* __restrict__ attb, const ushort* __restrict__ emb01,
    const ushort* __restrict__ emb23, const ushort* __restrict__ resb,
    float* __restrict__ out) {
  const int P = blockIdx.y;
  const ushort* emb_p = P ? emb23 : emb01;
  int n = blockIdx.x * 4 + (threadIdx.x >> 6);
  int lane = threadIdx.x & 63;
  float acc0 = 0.f, acc1 = 0.f;
  int e = min(cnt[n], CAP);
  for (int base = 0; base < e; base += 64) {
    int c = min(64, e - base);
    int src = 0;
    float a0 = 0.f, a1 = 0.f;
    if (lane < c) {
      src = srcb[(size_t)n * CAP + base + lane];
      ushort2 av = *(const ushort2*)&attb[((size_t)n * CAP + base + lane) * 4 + P * 2];
      a0 = bf2f(av.x);
      a1 = bf2f(av.y);
    }
#pragma unroll 4
    for (int j = 0; j < c; ++j) {
      int sj = __shfl(src, j);
      float b0 = __shfl(a0, j), b1 = __shfl(a1, j);
      ushort2 v = *(const ushort2*)&emb_p[((size_t)sj * 64 + lane) * 2];
      acc0 = fmaf(bf2f(v.x), b0, acc0);
      acc1 = fmaf(bf2f(v.y), b1, acc1);
    }
  }
  ushort2 r2 = *(const ushort2*)&resb[(size_t)n * 256 + lane * 4 + P * 2];
  float v0 = acc0 + bf2f(r2.x), v1 = acc1 + bf2f(r2.y);
  float2 o;
  o.x = v0 > 0.f ? v0 : expm1f(v0);
  o.y = v1 > 0.f ? v1 : expm1f(v1);
  *(float2*)&out[(size_t)n * 256 + lane * 4 + P * 2] = o;
}

extern "C" void kernel_launch(void* const* d_in, const int* in_sizes, int n_in,
                              void* d_out, int out_size, void* d_ws, size_t ws_size,
                              hipStream_t stream) {
  const float* feat = (const float*)d_in[0];
  const float* ew = (const float*)d_in[1];
  const int* row = (const int*)d_in[2];
  const int* col = (const int*)d_in[3];
  const int* etype = (const int*)d_in[4];
  const float* W = (const float*)d_in[5];
  const float* table = (const float*)d_in[6];
  const float* W_r = (const float*)d_in[7];
  const float* a_l = (const float*)d_in[8];
  const float* a_r = (const float*)d_in[9];
  const float* a_e = (const float*)d_in[10];
  const float* W_res = (const float*)d_in[11];
  const float* b_res = (const float*)d_in[12];
  float* out = (float*)d_out;

  char* w = (char*)d_ws;
  auto alloc = [&](size_t bytes) {
    char* pp = w;
    w += (bytes + 255) & ~(size_t)255;
    return pp;
  };
  ushort* Wtb = (ushort*)alloc((size_t)512 * 256 * 2);
  ushort* emb01 = (ushort*)alloc((size_t)N_NODES * 128 * 2);
  ushort* emb23 = (ushort*)alloc((size_t)N_NODES * 128 * 2);
  ushort* resb = (ushort*)alloc((size_t)N_NODES * 256 * 2);
  ushort* srcb = (ushort*)alloc((size_t)N_NODES * CAP * 2);
  ushort* attb = (ushort*)alloc((size_t)N_NODES * CAP * 4 * 2);
  float* hl = (float*)alloc((size_t)N_NODES * NH * 4);
  float* hr = (float*)alloc((size_t)N_NODES * NH * 4);
  float* he_type = (float*)alloc(NT * NH * 4);
  int* cnt = (int*)alloc((size_t)(N_NODES + 1) * 4);

  prep_kernel<<<(PREP_TOTAL + 255) / 256, 256, 0, stream>>>(
      W, W_res, table, W_r, a_e, Wtb, he_type, cnt);
  gemm_kernel<<<MPAD / 32, 512, 0, stream>>>(feat, Wtb, b_res, a_l, a_r,
                                             emb01, emb23, resb, hl, hr);
  scatter_kernel<<<(N_EDGES + 255) / 256, 256, 0, stream>>>(
      row, col, etype, ew, hl, hr, he_type, cnt, srcb, attb);
  agg_kernel<<<dim3(N_NODES / 4, 2), 256, 0, stream>>>(cnt, srcb, attb, emb01,
                                                       emb23, resb, out);
}

// Round 7
// 83.401 us; speedup vs baseline: 10.5892x; 1.2484x over previous
//
#include <hip/hip_runtime.h>
#include <hip/hip_bf16.h>
#include <math.h>

#define N_NODES 10000
#define MPAD 10112        // 316 * 32
#define N_EDGES 320000
#define IN_DIM 256
#define NH 4
#define EDIM 32
#define NT 8
#define SLOPE 0.2f
#define CAP 96            // bucket capacity per dst (Poisson(32): P(deg>96) ~ 1e-18)

#define WTW (512 * 256)           // Wtb items
#define ZCNT (N_NODES + 1)
#define PREP_TOTAL (WTW + 1024 + ZCNT)

typedef __attribute__((ext_vector_type(8))) short short8b;
typedef __attribute__((ext_vector_type(4))) float f32x4;

__device__ __forceinline__ float bf2f(ushort u) {
  return __uint_as_float(((unsigned)u) << 16);
}
__device__ __forceinline__ ushort f2bf(float f) {
  __hip_bfloat16 h = __float2bfloat16(f);
  return *(ushort*)&h;
}
__device__ __forceinline__ unsigned pk2(float a, float b) {
  return (unsigned)f2bf(a) | ((unsigned)f2bf(b) << 16);
}

// ---------------- prep: Wtb + he_type + zero cnt (small) ----------------
__global__ void prep_kernel(const float* __restrict__ W,
                            const float* __restrict__ W_res,
                            const float* __restrict__ table,
                            const float* __restrict__ W_r,
                            const float* __restrict__ a_e,
                            ushort* __restrict__ Wtb,
                            float* __restrict__ he_type,
                            int* __restrict__ cnt) {
  int i = blockIdx.x * 256 + threadIdx.x;
  if (i < WTW) {
    int c = i >> 8, k = i & 255;
    float v = (c < 256) ? W[k * 256 + c] : W_res[k * 256 + (c - 256)];
    Wtb[c * 256 + k] = f2bf(v);
  } else if (i < WTW + 1024) {
    int t2 = i - WTW;  // 0..1023 (block-aligned: WTW % 256 == 0)
    int t = t2 >> 7, h = (t2 >> 5) & 3, d = t2 & 31;
    float acc = 0.f;
    for (int q = 0; q < EDIM; ++q)
      acc += table[t * EDIM + q] * W_r[(t * EDIM + q) * (EDIM * NH) + h * EDIM + d];
    acc *= a_e[h * EDIM + d];
#pragma unroll
    for (int o = 16; o; o >>= 1) acc += __shfl_xor(acc, o, 32);
    if (d == 0) he_type[t * NH + h] = acc;
  } else if (i < PREP_TOTAL) {
    cnt[i - WTW - 1024] = 0;
  }
}

// ---------------- fused convert+GEMM: 32 rows x 512 cols per block, 8 waves ----------
// LDS-staged bf16 A tile (XOR-swizzled); B from global (L2-hot Wtb).
// cols<256 -> emb_t [n][d][h] + hl/hr ; cols>=256 -> resb (bf16) + b_res.
__global__ __launch_bounds__(512) void gemm_kernel(
    const float* __restrict__ feat, const ushort* __restrict__ Wtb,
    const float* __restrict__ b_res,
    const float* __restrict__ a_l, const float* __restrict__ a_r,
    ushort* __restrict__ emb_t, ushort* __restrict__ resb,
    float* __restrict__ hl, float* __restrict__ hr) {
  __shared__ ushort As[32 * 256];  // 16 KB, [row][k] with 16B-chunk XOR swizzle
  const int tid = threadIdx.x;
  const int rowbase = blockIdx.x * 32;

  // stage: 32 rows x 256 k fp32 -> bf16 LDS (coalesced float4 loads)
#pragma unroll
  for (int i = 0; i < 2; ++i) {
    int c = tid + i * 512;           // chunk id: 1024 chunks of 16B
    int rowl = c >> 5, slot = c & 31;
    int gr = rowbase + rowl;
    uint4 pk = make_uint4(0, 0, 0, 0);
    if (gr < N_NODES) {
      float4 x = *(const float4*)&feat[(size_t)gr * 256 + slot * 8];
      float4 y = *(const float4*)&feat[(size_t)gr * 256 + slot * 8 + 4];
      pk.x = pk2(x.x, x.y); pk.y = pk2(x.z, x.w);
      pk.z = pk2(y.x, y.y); pk.w = pk2(y.z, y.w);
    }
    int idx = rowl * 256 + (((slot * 16) ^ ((rowl & 7) << 4)) >> 1);
    *(uint4*)&As[idx] = pk;
  }
  __syncthreads();

  const int wave = tid >> 6, lane = tid & 63;
  const int col0 = wave * 64;
  const int lr = lane & 15;
  const int lkq = lane >> 4;        // k-quarter
  f32x4 acc[2][4] = {};
  const ushort* Bb = Wtb + (size_t)(col0 + lr) * 256 + lkq * 8;

#pragma unroll
  for (int ks = 0; ks < 8; ++ks) {
    short8b a[2], b[4];
#pragma unroll
    for (int m = 0; m < 2; ++m) {
      int rowl = m * 16 + lr;
      int kb = ks * 64 + lkq * 16;  // byte offset in row
      int idx = rowl * 256 + ((kb ^ ((rowl & 7) << 4)) >> 1);
      a[m] = *(const short8b*)&As[idx];
    }
#pragma unroll
    for (int n = 0; n < 4; ++n)
      b[n] = *(const short8b*)(Bb + (size_t)(n * 16) * 256 + ks * 32);
#pragma unroll
    for (int m = 0; m < 2; ++m)
#pragma unroll
      for (int n = 0; n < 4; ++n)
        acc[m][n] = __builtin_amdgcn_mfma_f32_16x16x32_bf16(a[m], b[n], acc[m][n], 0, 0, 0);
  }

  const int rbase = rowbase + lkq * 4;
  if (col0 < 256) {
    const int h = col0 >> 6;         // head = wave (0..3)
#pragma unroll
    for (int m = 0; m < 2; ++m)
#pragma unroll
      for (int n = 0; n < 4; ++n) {
        int d = (n * 16 + lr) & 63;
#pragma unroll
        for (int j = 0; j < 4; ++j) {
          int r = rbase + m * 16 + j;
          if (r < N_NODES)
            emb_t[((size_t)r * 64 + d) * 4 + h] = f2bf(acc[m][n][j]);
        }
      }
    float al[4], ar[4];
#pragma unroll
    for (int n = 0; n < 4; ++n) {
      al[n] = a_l[h * 64 + n * 16 + lr];
      ar[n] = a_r[h * 64 + n * 16 + lr];
    }
#pragma unroll
    for (int m = 0; m < 2; ++m)
#pragma unroll
      for (int j = 0; j < 4; ++j) {
        float pl = acc[m][0][j] * al[0] + acc[m][1][j] * al[1] +
                   acc[m][2][j] * al[2] + acc[m][3][j] * al[3];
        float pr = acc[m][0][j] * ar[0] + acc[m][1][j] * ar[1] +
                   acc[m][2][j] * ar[2] + acc[m][3][j] * ar[3];
#pragma unroll
        for (int o = 1; o < 16; o <<= 1) {
          pl += __shfl_xor(pl, o);
          pr += __shfl_xor(pr, o);
        }
        int r = rbase + m * 16 + j;
        if (lr == 0 && r < N_NODES) {
          hl[r * 4 + h] = pl;
          hr[r * 4 + h] = pr;
        }
      }
  } else {
#pragma unroll
    for (int m = 0; m < 2; ++m)
#pragma unroll
      for (int n = 0; n < 4; ++n) {
        int c = (col0 - 256) + n * 16 + lr;
        float br = b_res[c];
#pragma unroll
        for (int j = 0; j < 4; ++j) {
          int r = rbase + m * 16 + j;
          if (r < N_NODES) resb[(size_t)r * 256 + c] = f2bf(acc[m][n][j] + br);
        }
      }
  }
}

// ---------------- attention + bucket scatter ----------------
__global__ void scatter_kernel(const int* __restrict__ row,
                               const int* __restrict__ colv,
                               const int* __restrict__ et,
                               const float* __restrict__ ew,
                               const float* __restrict__ hl,
                               const float* __restrict__ hr,
                               const float* __restrict__ he_type,
                               int* cnt, ushort* __restrict__ srcb,
                               ushort* __restrict__ attb) {
  int e = blockIdx.x * 256 + threadIdx.x;
  if (e >= N_EDGES) return;
  int r = row[e], c = colv[e], t = et[e];
  float w = ew[e];
  float4 L = *(const float4*)&hl[r * 4];
  float4 R = *(const float4*)&hr[c * 4];
  float4 Hh = *(const float4*)&he_type[t * 4];
  float x[4] = {L.x + R.x + Hh.x, L.y + R.y + Hh.y, L.z + R.z + Hh.z, L.w + R.w + Hh.w};
  ushort4 ab;
  ushort* ap = (ushort*)&ab;
#pragma unroll
  for (int h = 0; h < 4; ++h) {
    float v = x[h];
    v = v >= 0.f ? v : SLOPE * v;
    ap[h] = f2bf(w / (1.f + expf(-v)));
  }
  int s = atomicAdd(&cnt[c], 1);
  if (s < CAP) {
    srcb[(size_t)c * CAP + s] = (ushort)r;
    *(ushort4*)&attb[((size_t)c * CAP + s) * 4] = ab;
  }
}

// ---------------- aggregation: wave per dst node, scalar metadata, 4 heads/pass ----
__global__ __launch_bounds__(256) void agg_kernel(
    const int* __restrict__ cnt, const ushort* __restrict__ srcb,
    const ushort* __restrict__ attb, const ushort* __restrict__ emb_t,
    const ushort* __restrict__ resb, float* __restrict__ out) {
  const int nu = __builtin_amdgcn_readfirstlane(blockIdx.x * 4 + (threadIdx.x >> 6));
  const int lane = threadIdx.x & 63;
  float acc0 = 0.f, acc1 = 0.f, acc2 = 0.f, acc3 = 0.f;
  const int e = min(cnt[nu], CAP);
  const ushort* sb = srcb + (size_t)nu * CAP;
  const ushort* ab = attb + (size_t)nu * CAP * 4;

#define AGG_FMA(V, WA, WB)                                      \
  acc0 = fmaf(bf2f((V).x), __uint_as_float((WA) << 16), acc0);  \
  acc1 = fmaf(bf2f((V).y), __uint_as_float((WA) & 0xffff0000u), acc1); \
  acc2 = fmaf(bf2f((V).z), __uint_as_float((WB) << 16), acc2);  \
  acc3 = fmaf(bf2f((V).w), __uint_as_float((WB) & 0xffff0000u), acc3);

  const int j4 = e & ~3;
  for (int j = 0; j < j4; j += 4) {
    uint2 sw = *(const uint2*)&sb[j];              // 4 src ids (scalar load)
    uint4 wa = *(const uint4*)&ab[(size_t)j * 4];  // atts edges j, j+1
    uint4 wb = *(const uint4*)&ab[(size_t)(j + 2) * 4];  // atts edges j+2, j+3
    int s0 = sw.x & 0xffff, s1 = sw.x >> 16;
    int s2 = sw.y & 0xffff, s3 = sw.y >> 16;
    ushort4 v0 = *(const ushort4*)&emb_t[((size_t)s0 * 64 + lane) * 4];
    ushort4 v1 = *(const ushort4*)&emb_t[((size_t)s1 * 64 + lane) * 4];
    ushort4 v2 = *(const ushort4*)&emb_t[((size_t)s2 * 64 + lane) * 4];
    ushort4 v3 = *(const ushort4*)&emb_t[((size_t)s3 * 64 + lane) * 4];
    AGG_FMA(v0, wa.x, wa.y)
    AGG_FMA(v1, wa.z, wa.w)
    AGG_FMA(v2, wb.x, wb.y)
    AGG_FMA(v3, wb.z, wb.w)
  }
  for (int j = j4; j < e; ++j) {
    int s0 = sb[j];
    uint2 wa = *(const uint2*)&ab[(size_t)j * 4];
    ushort4 v0 = *(const ushort4*)&emb_t[((size_t)s0 * 64 + lane) * 4];
    AGG_FMA(v0, wa.x, wa.y)
  }
#undef AGG_FMA

  ushort4 r4 = *(const ushort4*)&resb[((size_t)nu * 64 + lane) * 4];
  float v0 = acc0 + bf2f(r4.x), v1 = acc1 + bf2f(r4.y);
  float v2 = acc2 + bf2f(r4.z), v3 = acc3 + bf2f(r4.w);
  float4 o;
  o.x = v0 > 0.f ? v0 : expm1f(v0);
  o.y = v1 > 0.f ? v1 : expm1f(v1);
  o.z = v2 > 0.f ? v2 : expm1f(v2);
  o.w = v3 > 0.f ? v3 : expm1f(v3);
  *(float4*)&out[((size_t)nu * 64 + lane) * 4] = o;
}

extern "C" void kernel_launch(void* const* d_in, const int* in_sizes, int n_in,
                              void* d_out, int out_size, void* d_ws, size_t ws_size,
                              hipStream_t stream) {
  const float* feat = (const float*)d_in[0];
  const float* ew = (const float*)d_in[1];
  const int* row = (const int*)d_in[2];
  const int* col = (const int*)d_in[3];
  const int* etype = (const int*)d_in[4];
  const float* W = (const float*)d_in[5];
  const float* table = (const float*)d_in[6];
  const float* W_r = (const float*)d_in[7];
  const float* a_l = (const float*)d_in[8];
  const float* a_r = (const float*)d_in[9];
  const float* a_e = (const float*)d_in[10];
  const float* W_res = (const float*)d_in[11];
  const float* b_res = (const float*)d_in[12];
  float* out = (float*)d_out;

  char* w = (char*)d_ws;
  auto alloc = [&](size_t bytes) {
    char* pp = w;
    w += (bytes + 255) & ~(size_t)255;
    return pp;
  };
  ushort* Wtb = (ushort*)alloc((size_t)512 * 256 * 2);
  ushort* emb_t = (ushort*)alloc((size_t)N_NODES * 256 * 2);  // [n][d][h] bf16
  ushort* resb = (ushort*)alloc((size_t)N_NODES * 256 * 2);   // [n][d][h] bf16
  ushort* srcb = (ushort*)alloc((size_t)N_NODES * CAP * 2);
  ushort* attb = (ushort*)alloc((size_t)N_NODES * CAP * 4 * 2);
  float* hl = (float*)alloc((size_t)N_NODES * NH * 4);
  float* hr = (float*)alloc((size_t)N_NODES * NH * 4);
  float* he_type = (float*)alloc(NT * NH * 4);
  int* cnt = (int*)alloc((size_t)(N_NODES + 1) * 4);

  prep_kernel<<<(PREP_TOTAL + 255) / 256, 256, 0, stream>>>(
      W, W_res, table, W_r, a_e, Wtb, he_type, cnt);
  gemm_kernel<<<MPAD / 32, 512, 0, stream>>>(feat, Wtb, b_res, a_l, a_r,
                                             emb_t, resb, hl, hr);
  scatter_kernel<<<(N_EDGES + 255) / 256, 256, 0, stream>>>(
      row, col, etype, ew, hl, hr, he_type, cnt, srcb, attb);
  agg_kernel<<<N_NODES / 4, 256, 0, stream>>>(cnt, srcb, attb, emb_t, resb, out);
}

// Round 8
// 78.586 us; speedup vs baseline: 11.2379x; 1.0613x over previous
//
#include <hip/hip_runtime.h>
#include <hip/hip_bf16.h>
#include <math.h>

#define N_NODES 10000
#define MPAD 10112        // 316 * 32
#define N_EDGES 320000
#define IN_DIM 256
#define NH 4
#define EDIM 32
#define NT 8
#define SLOPE 0.2f
#define CAP 96            // bucket capacity per dst (Poisson(32): P(deg>96) ~ 1e-18)

#define WTW (512 * 256)           // Wtb items
#define ZCNT (N_NODES + 1)
#define PREP_TOTAL (WTW + 1024 + ZCNT)

typedef __attribute__((ext_vector_type(8))) short short8b;
typedef __attribute__((ext_vector_type(4))) float f32x4;

__device__ __forceinline__ float bf2f(ushort u) {
  return __uint_as_float(((unsigned)u) << 16);
}
__device__ __forceinline__ ushort f2bf(float f) {
  __hip_bfloat16 h = __float2bfloat16(f);
  return *(ushort*)&h;
}
__device__ __forceinline__ unsigned pk2(float a, float b) {
  return (unsigned)f2bf(a) | ((unsigned)f2bf(b) << 16);
}

// ---------------- prep: Wtb + he_type + zero cnt (small) ----------------
// Wtb row c (c<256): W column ((c&3)*64 + (c>>2))  [emb cols reordered to d*4+h]
// Wtb row c (c>=256): W_res column (c-256)         [already d*4+h]
__global__ void prep_kernel(const float* __restrict__ W,
                            const float* __restrict__ W_res,
                            const float* __restrict__ table,
                            const float* __restrict__ W_r,
                            const float* __restrict__ a_e,
                            ushort* __restrict__ Wtb,
                            float* __restrict__ he_type,
                            int* __restrict__ cnt) {
  int i = blockIdx.x * 256 + threadIdx.x;
  if (i < WTW) {
    int c = i >> 8, k = i & 255;
    float v = (c < 256) ? W[k * 256 + ((c & 3) * 64 + (c >> 2))]
                        : W_res[k * 256 + (c - 256)];
    Wtb[c * 256 + k] = f2bf(v);
  } else if (i < WTW + 1024) {
    int t2 = i - WTW;  // 0..1023 (block-aligned: WTW % 256 == 0)
    int t = t2 >> 7, h = (t2 >> 5) & 3, d = t2 & 31;
    float acc = 0.f;
    for (int q = 0; q < EDIM; ++q)
      acc += table[t * EDIM + q] * W_r[(t * EDIM + q) * (EDIM * NH) + h * EDIM + d];
    acc *= a_e[h * EDIM + d];
#pragma unroll
    for (int o = 16; o; o >>= 1) acc += __shfl_xor(acc, o, 32);
    if (d == 0) he_type[t * NH + h] = acc;
  } else if (i < PREP_TOTAL) {
    cnt[i - WTW - 1024] = 0;
  }
}

// ---------------- fused convert+GEMM, operand-swapped MFMA ----------------
// 32 rows x 512 cols per block, 8 waves. acc = mfma(b, a) -> C^T:
//   output col (lane&15) = feat row r ; output row ((lane>>4)*4+j) = Wt col c.
// Thread holds 4 consecutive c (= d*4 + h0..3 for emb) -> packed ushort4 stores.
__global__ __launch_bounds__(512) void gemm_kernel(
    const float* __restrict__ feat, const ushort* __restrict__ Wtb,
    const float* __restrict__ b_res,
    const float* __restrict__ a_l, const float* __restrict__ a_r,
    ushort* __restrict__ emb_t, ushort* __restrict__ resb,
    float* __restrict__ hl, float* __restrict__ hr) {
  __shared__ ushort As[32 * 256];  // 16 KB, [row][k] with 16B-chunk XOR swizzle
  const int tid = threadIdx.x;
  const int rowbase = blockIdx.x * 32;

  // stage: 32 rows x 256 k fp32 -> bf16 LDS (coalesced float4 loads)
#pragma unroll
  for (int i = 0; i < 2; ++i) {
    int c = tid + i * 512;           // chunk id: 1024 chunks of 16B
    int rowl = c >> 5, slot = c & 31;
    int gr = rowbase + rowl;
    uint4 pk = make_uint4(0, 0, 0, 0);
    if (gr < N_NODES) {
      float4 x = *(const float4*)&feat[(size_t)gr * 256 + slot * 8];
      float4 y = *(const float4*)&feat[(size_t)gr * 256 + slot * 8 + 4];
      pk.x = pk2(x.x, x.y); pk.y = pk2(x.z, x.w);
      pk.z = pk2(y.x, y.y); pk.w = pk2(y.z, y.w);
    }
    int idx = rowl * 256 + (((slot * 16) ^ ((rowl & 7) << 4)) >> 1);
    *(uint4*)&As[idx] = pk;
  }
  __syncthreads();

  const int wave = tid >> 6, lane = tid & 63;
  const int col0 = wave * 64;
  const int lr = lane & 15;
  const int lkq = lane >> 4;        // k-quarter
  f32x4 acc[4][2] = {};             // [n][m]
  const ushort* Bb = Wtb + (size_t)(col0 + lr) * 256 + lkq * 8;

#pragma unroll
  for (int ks = 0; ks < 8; ++ks) {
    short8b a[2], b[4];
#pragma unroll
    for (int m = 0; m < 2; ++m) {
      int rowl = m * 16 + lr;
      int kb = ks * 64 + lkq * 16;  // byte offset in row
      int idx = rowl * 256 + ((kb ^ ((rowl & 7) << 4)) >> 1);
      a[m] = *(const short8b*)&As[idx];
    }
#pragma unroll
    for (int n = 0; n < 4; ++n)
      b[n] = *(const short8b*)(Bb + (size_t)(n * 16) * 256 + ks * 32);
#pragma unroll
    for (int n = 0; n < 4; ++n)
#pragma unroll
      for (int m = 0; m < 2; ++m)
        acc[n][m] = __builtin_amdgcn_mfma_f32_16x16x32_bf16(b[n], a[m], acc[n][m], 0, 0, 0);
  }

  float pl[2][4] = {{0.f}}, pr[2][4] = {{0.f}};
  if (col0 < 256) {
    // packed emb_t stores: thread has (r, d) -> all 4 heads
#pragma unroll
    for (int m = 0; m < 2; ++m) {
      int r = rowbase + m * 16 + lr;
      if (r < N_NODES) {
#pragma unroll
        for (int n = 0; n < 4; ++n) {
          int d = (col0 >> 2) + n * 4 + lkq;
          ushort4 pk4;
          pk4.x = f2bf(acc[n][m][0]); pk4.y = f2bf(acc[n][m][1]);
          pk4.z = f2bf(acc[n][m][2]); pk4.w = f2bf(acc[n][m][3]);
          *(ushort4*)&emb_t[((size_t)r * 64 + d) * 4] = pk4;
        }
      }
    }
    // hl/hr partials over this wave's 16 d values (j == h)
#pragma unroll
    for (int n = 0; n < 4; ++n) {
      int d = (col0 >> 2) + n * 4 + lkq;
#pragma unroll
      for (int h = 0; h < 4; ++h) {
        float alv = a_l[h * 64 + d];
        float arv = a_r[h * 64 + d];
#pragma unroll
        for (int m = 0; m < 2; ++m) {
          pl[m][h] = fmaf(acc[n][m][h], alv, pl[m][h]);
          pr[m][h] = fmaf(acc[n][m][h], arv, pr[m][h]);
        }
      }
    }
    // reduce over lkq (lanes ^16, ^32)
#pragma unroll
    for (int m = 0; m < 2; ++m)
#pragma unroll
      for (int h = 0; h < 4; ++h) {
        pl[m][h] += __shfl_xor(pl[m][h], 16);
        pl[m][h] += __shfl_xor(pl[m][h], 32);
        pr[m][h] += __shfl_xor(pr[m][h], 16);
        pr[m][h] += __shfl_xor(pr[m][h], 32);
      }
  } else {
    // packed resb stores (+ bias)
#pragma unroll
    for (int m = 0; m < 2; ++m) {
      int r = rowbase + m * 16 + lr;
      if (r < N_NODES) {
#pragma unroll
        for (int n = 0; n < 4; ++n) {
          int c = (col0 - 256) + n * 16 + lkq * 4;
          float4 br = *(const float4*)&b_res[c];
          ushort4 pk4;
          pk4.x = f2bf(acc[n][m][0] + br.x); pk4.y = f2bf(acc[n][m][1] + br.y);
          pk4.z = f2bf(acc[n][m][2] + br.z); pk4.w = f2bf(acc[n][m][3] + br.w);
          *(ushort4*)&resb[(size_t)r * 256 + c] = pk4;
        }
      }
    }
  }

  // cross-wave hl/hr combine via LDS (reuse As after barrier)
  float* PL = (float*)As;           // [4 waves][32 r][4 h]
  float* PR = PL + 512;
  __syncthreads();
  if (col0 < 256 && lkq == 0) {
#pragma unroll
    for (int m = 0; m < 2; ++m)
#pragma unroll
      for (int h = 0; h < 4; ++h) {
        PL[(wave * 32 + m * 16 + lr) * 4 + h] = pl[m][h];
        PR[(wave * 32 + m * 16 + lr) * 4 + h] = pr[m][h];
      }
  }
  __syncthreads();
  if (tid < 64) {
    int rl = tid >> 1, sel = tid & 1;
    const float* P = sel ? PR : PL;
    float4 v;
    v.x = P[rl * 4 + 0] + P[128 + rl * 4 + 0] + P[256 + rl * 4 + 0] + P[384 + rl * 4 + 0];
    v.y = P[rl * 4 + 1] + P[128 + rl * 4 + 1] + P[256 + rl * 4 + 1] + P[384 + rl * 4 + 1];
    v.z = P[rl * 4 + 2] + P[128 + rl * 4 + 2] + P[256 + rl * 4 + 2] + P[384 + rl * 4 + 2];
    v.w = P[rl * 4 + 3] + P[128 + rl * 4 + 3] + P[256 + rl * 4 + 3] + P[384 + rl * 4 + 3];
    int r = rowbase + rl;
    if (r < N_NODES) *(float4*)&(sel ? hr : hl)[r * 4] = v;
  }
}

// ---------------- attention + bucket scatter: one 16B slot per edge ----------------
__global__ void scatter_kernel(const int* __restrict__ row,
                               const int* __restrict__ colv,
                               const int* __restrict__ et,
                               const float* __restrict__ ew,
                               const float* __restrict__ hl,
                               const float* __restrict__ hr,
                               const float* __restrict__ he_type,
                               int* cnt, uint4* __restrict__ slots) {
  int e = blockIdx.x * 256 + threadIdx.x;
  if (e >= N_EDGES) return;
  int r = row[e], c = colv[e], t = et[e];
  float w = ew[e];
  float4 L = *(const float4*)&hl[r * 4];
  float4 R = *(const float4*)&hr[c * 4];
  float4 Hh = *(const float4*)&he_type[t * 4];
  float x[4] = {L.x + R.x + Hh.x, L.y + R.y + Hh.y, L.z + R.z + Hh.z, L.w + R.w + Hh.w};
  float a[4];
#pragma unroll
  for (int h = 0; h < 4; ++h) {
    float v = x[h];
    v = v >= 0.f ? v : SLOPE * v;
    a[h] = w / (1.f + expf(-v));
  }
  uint4 slot;
  slot.x = pk2(a[0], a[1]);
  slot.y = pk2(a[2], a[3]);
  slot.z = (unsigned)r;
  slot.w = 0;
  int s = atomicAdd(&cnt[c], 1);
  if (s < CAP) slots[(size_t)c * CAP + s] = slot;
}

// ---------------- aggregation: wave per dst node, uniform slot loads ----------------
__global__ __launch_bounds__(256) void agg_kernel(
    const int* __restrict__ cnt, const uint4* __restrict__ slots,
    const ushort* __restrict__ emb_t, const ushort* __restrict__ resb,
    float* __restrict__ out) {
  const int nu = __builtin_amdgcn_readfirstlane(blockIdx.x * 4 + (threadIdx.x >> 6));
  const int lane = threadIdx.x & 63;
  float acc0 = 0.f, acc1 = 0.f, acc2 = 0.f, acc3 = 0.f;
  const int e = min(cnt[nu], CAP);
  const uint4* ab = slots + (size_t)nu * CAP;

#define AGG_FMA(V, WA, WB)                                      \
  acc0 = fmaf(bf2f((V).x), __uint_as_float((WA) << 16), acc0);  \
  acc1 = fmaf(bf2f((V).y), __uint_as_float((WA) & 0xffff0000u), acc1); \
  acc2 = fmaf(bf2f((V).z), __uint_as_float((WB) << 16), acc2);  \
  acc3 = fmaf(bf2f((V).w), __uint_as_float((WB) & 0xffff0000u), acc3);

  const int j4 = e & ~3;
#pragma unroll 2
  for (int j = 0; j < j4; j += 4) {
    uint4 s0 = ab[j], s1 = ab[j + 1], s2 = ab[j + 2], s3 = ab[j + 3];
    ushort4 v0 = *(const ushort4*)&emb_t[((size_t)s0.z * 64 + lane) * 4];
    ushort4 v1 = *(const ushort4*)&emb_t[((size_t)s1.z * 64 + lane) * 4];
    ushort4 v2 = *(const ushort4*)&emb_t[((size_t)s2.z * 64 + lane) * 4];
    ushort4 v3 = *(const ushort4*)&emb_t[((size_t)s3.z * 64 + lane) * 4];
    AGG_FMA(v0, s0.x, s0.y)
    AGG_FMA(v1, s1.x, s1.y)
    AGG_FMA(v2, s2.x, s2.y)
    AGG_FMA(v3, s3.x, s3.y)
  }
  for (int j = j4; j < e; ++j) {
    uint4 s0 = ab[j];
    ushort4 v0 = *(const ushort4*)&emb_t[((size_t)s0.z * 64 + lane) * 4];
    AGG_FMA(v0, s0.x, s0.y)
  }
#undef AGG_FMA

  ushort4 r4 = *(const ushort4*)&resb[((size_t)nu * 64 + lane) * 4];
  float v0 = acc0 + bf2f(r4.x), v1 = acc1 + bf2f(r4.y);
  float v2 = acc2 + bf2f(r4.z), v3 = acc3 + bf2f(r4.w);
  float4 o;
  o.x = v0 > 0.f ? v0 : expm1f(v0);
  o.y = v1 > 0.f ? v1 : expm1f(v1);
  o.z = v2 > 0.f ? v2 : expm1f(v2);
  o.w = v3 > 0.f ? v3 : expm1f(v3);
  *(float4*)&out[((size_t)nu * 64 + lane) * 4] = o;
}

extern "C" void kernel_launch(void* const* d_in, const int* in_sizes, int n_in,
                              void* d_out, int out_size, void* d_ws, size_t ws_size,
                              hipStream_t stream) {
  const float* feat = (const float*)d_in[0];
  const float* ew = (const float*)d_in[1];
  const int* row = (const int*)d_in[2];
  const int* col = (const int*)d_in[3];
  const int* etype = (const int*)d_in[4];
  const float* W = (const float*)d_in[5];
  const float* table = (const float*)d_in[6];
  const float* W_r = (const float*)d_in[7];
  const float* a_l = (const float*)d_in[8];
  const float* a_r = (const float*)d_in[9];
  const float* a_e = (const float*)d_in[10];
  const float* W_res = (const float*)d_in[11];
  const float* b_res = (const float*)d_in[12];
  float* out = (float*)d_out;

  char* w = (char*)d_ws;
  auto alloc = [&](size_t bytes) {
    char* pp = w;
    w += (bytes + 255) & ~(size_t)255;
    return pp;
  };
  ushort* Wtb = (ushort*)alloc((size_t)512 * 256 * 2);
  ushort* emb_t = (ushort*)alloc((size_t)N_NODES * 256 * 2);  // [n][d][h] bf16
  ushort* resb = (ushort*)alloc((size_t)N_NODES * 256 * 2);   // [n][d*4+h] bf16
  uint4* slots = (uint4*)alloc((size_t)N_NODES * CAP * 16);   // {att01, att23, src, 0}
  float* hl = (float*)alloc((size_t)N_NODES * NH * 4);
  float* hr = (float*)alloc((size_t)N_NODES * NH * 4);
  float* he_type = (float*)alloc(NT * NH * 4);
  int* cnt = (int*)alloc((size_t)(N_NODES + 1) * 4);

  prep_kernel<<<(PREP_TOTAL + 255) / 256, 256, 0, stream>>>(
      W, W_res, table, W_r, a_e, Wtb, he_type, cnt);
  gemm_kernel<<<MPAD / 32, 512, 0, stream>>>(feat, Wtb, b_res, a_l, a_r,
                                             emb_t, resb, hl, hr);
  scatter_kernel<<<(N_EDGES + 255) / 256, 256, 0, stream>>>(
      row, col, etype, ew, hl, hr, he_type, cnt, slots);
  agg_kernel<<<N_NODES / 4, 256, 0, stream>>>(cnt, slots, emb_t, resb, out);
}

// Round 9
// 57.732 us; speedup vs baseline: 15.2973x; 1.3612x over previous
//
#include <hip/hip_runtime.h>
#include <hip/hip_bf16.h>
#include <math.h>

#define N_NODES 10000
#define MPAD 10112        // 316 * 32
#define N_EDGES 320000
#define IN_DIM 256
#define NH 4
#define EDIM 32
#define NT 8
#define SLOPE 0.2f
#define CAP 96            // bucket capacity per dst (Poisson(32): P(deg>96) ~ 1e-18)

#define WTW (512 * 256)           // Wtb items
#define GB (MPAD / 32)            // 316 gemm blocks
#define EBT 512                   // edges per bucket block
#define EB ((N_EDGES + EBT - 1) / EBT)  // 625 bucket blocks

typedef __attribute__((ext_vector_type(8))) short short8b;
typedef __attribute__((ext_vector_type(4))) float f32x4;

__device__ __forceinline__ float bf2f(ushort u) {
  return __uint_as_float(((unsigned)u) << 16);
}
__device__ __forceinline__ ushort f2bf(float f) {
  __hip_bfloat16 h = __float2bfloat16(f);
  return *(ushort*)&h;
}
__device__ __forceinline__ unsigned pk2(float a, float b) {
  return (unsigned)f2bf(a) | ((unsigned)f2bf(b) << 16);
}

// ---------------- prep: Wtb + he_type + zero cnt ----------------
// Wtb row c (c<256): W column ((c&3)*64 + (c>>2))  [emb cols reordered to d*4+h]
// Wtb row c (c>=256): W_res column (c-256)         [already d*4+h]
__global__ void prep_kernel(const float* __restrict__ W,
                            const float* __restrict__ W_res,
                            const float* __restrict__ table,
                            const float* __restrict__ W_r,
                            const float* __restrict__ a_e,
                            ushort* __restrict__ Wtb,
                            float* __restrict__ he_type,
                            int* __restrict__ cnt) {
  int i = blockIdx.x * 256 + threadIdx.x;
  if (i < WTW) {
    int c = i >> 8, k = i & 255;
    float v = (c < 256) ? W[k * 256 + ((c & 3) * 64 + (c >> 2))]
                        : W_res[k * 256 + (c - 256)];
    Wtb[c * 256 + k] = f2bf(v);
  } else if (i < WTW + 1024) {
    int t2 = i - WTW;  // 0..1023
    int t = t2 >> 7, h = (t2 >> 5) & 3, d = t2 & 31;
    float acc = 0.f;
    for (int q = 0; q < EDIM; ++q)
      acc += table[t * EDIM + q] * W_r[(t * EDIM + q) * (EDIM * NH) + h * EDIM + d];
    acc *= a_e[h * EDIM + d];
#pragma unroll
    for (int o = 16; o; o >>= 1) acc += __shfl_xor(acc, o, 32);
    if (d == 0) he_type[t * NH + h] = acc;
  } else {
    int z = i - WTW - 1024;
    if (z <= N_NODES) cnt[z] = 0;
  }
}

// ---------------- K2: gemm blocks (0..GB-1) + bucket-fill blocks (GB..GB+EB-1) ---
// GEMM: 32 rows x 512 cols per block, 8 waves, operand-swapped MFMA (round-8 proven).
// Bucket: one edge per thread -> slot {et<<16|src, ew_bits} at cnt[dst]++.
__global__ __launch_bounds__(512) void gemm_bucket_kernel(
    const float* __restrict__ feat, const ushort* __restrict__ Wtb,
    const float* __restrict__ b_res,
    const float* __restrict__ a_l, const float* __restrict__ a_r,
    ushort* __restrict__ emb_t, ushort* __restrict__ resb,
    float* __restrict__ hl, float* __restrict__ hr,
    const int* __restrict__ row, const int* __restrict__ colv,
    const int* __restrict__ et, const float* __restrict__ ew,
    int* cnt, uint2* __restrict__ slots) {
  __shared__ ushort As[32 * 256];  // 16 KB
  const int tid = threadIdx.x;

  if (blockIdx.x >= GB) {
    // ---- bucket-fill role ----
    int e = (blockIdx.x - GB) * EBT + tid;
    if (e < N_EDGES) {
      int r = row[e], c = colv[e], t = et[e];
      float w = ew[e];
      uint2 slot;
      slot.x = ((unsigned)t << 16) | (unsigned)r;
      slot.y = __float_as_uint(w);
      int s = atomicAdd(&cnt[c], 1);
      if (s < CAP) slots[(size_t)c * CAP + s] = slot;
    }
    return;
  }

  // ---- gemm role ----
  const int rowbase = blockIdx.x * 32;

  // stage: 32 rows x 256 k fp32 -> bf16 LDS (16B-chunk XOR swizzle)
#pragma unroll
  for (int i = 0; i < 2; ++i) {
    int c = tid + i * 512;
    int rowl = c >> 5, slot = c & 31;
    int gr = rowbase + rowl;
    uint4 pk = make_uint4(0, 0, 0, 0);
    if (gr < N_NODES) {
      float4 x = *(const float4*)&feat[(size_t)gr * 256 + slot * 8];
      float4 y = *(const float4*)&feat[(size_t)gr * 256 + slot * 8 + 4];
      pk.x = pk2(x.x, x.y); pk.y = pk2(x.z, x.w);
      pk.z = pk2(y.x, y.y); pk.w = pk2(y.z, y.w);
    }
    int idx = rowl * 256 + (((slot * 16) ^ ((rowl & 7) << 4)) >> 1);
    *(uint4*)&As[idx] = pk;
  }
  __syncthreads();

  const int wave = tid >> 6, lane = tid & 63;
  const int col0 = wave * 64;
  const int lr = lane & 15;
  const int lkq = lane >> 4;
  f32x4 acc[4][2] = {};             // [n][m]
  const ushort* Bb = Wtb + (size_t)(col0 + lr) * 256 + lkq * 8;

#pragma unroll
  for (int ks = 0; ks < 8; ++ks) {
    short8b a[2], b[4];
#pragma unroll
    for (int m = 0; m < 2; ++m) {
      int rowl = m * 16 + lr;
      int kb = ks * 64 + lkq * 16;
      int idx = rowl * 256 + ((kb ^ ((rowl & 7) << 4)) >> 1);
      a[m] = *(const short8b*)&As[idx];
    }
#pragma unroll
    for (int n = 0; n < 4; ++n)
      b[n] = *(const short8b*)(Bb + (size_t)(n * 16) * 256 + ks * 32);
#pragma unroll
    for (int n = 0; n < 4; ++n)
#pragma unroll
      for (int m = 0; m < 2; ++m)
        acc[n][m] = __builtin_amdgcn_mfma_f32_16x16x32_bf16(b[n], a[m], acc[n][m], 0, 0, 0);
  }

  float pl[2][4] = {{0.f}}, pr[2][4] = {{0.f}};
  if (col0 < 256) {
#pragma unroll
    for (int m = 0; m < 2; ++m) {
      int r = rowbase + m * 16 + lr;
      if (r < N_NODES) {
#pragma unroll
        for (int n = 0; n < 4; ++n) {
          int d = (col0 >> 2) + n * 4 + lkq;
          ushort4 pk4;
          pk4.x = f2bf(acc[n][m][0]); pk4.y = f2bf(acc[n][m][1]);
          pk4.z = f2bf(acc[n][m][2]); pk4.w = f2bf(acc[n][m][3]);
          *(ushort4*)&emb_t[((size_t)r * 64 + d) * 4] = pk4;
        }
      }
    }
#pragma unroll
    for (int n = 0; n < 4; ++n) {
      int d = (col0 >> 2) + n * 4 + lkq;
#pragma unroll
      for (int h = 0; h < 4; ++h) {
        float alv = a_l[h * 64 + d];
        float arv = a_r[h * 64 + d];
#pragma unroll
        for (int m = 0; m < 2; ++m) {
          pl[m][h] = fmaf(acc[n][m][h], alv, pl[m][h]);
          pr[m][h] = fmaf(acc[n][m][h], arv, pr[m][h]);
        }
      }
    }
#pragma unroll
    for (int m = 0; m < 2; ++m)
#pragma unroll
      for (int h = 0; h < 4; ++h) {
        pl[m][h] += __shfl_xor(pl[m][h], 16);
        pl[m][h] += __shfl_xor(pl[m][h], 32);
        pr[m][h] += __shfl_xor(pr[m][h], 16);
        pr[m][h] += __shfl_xor(pr[m][h], 32);
      }
  } else {
#pragma unroll
    for (int m = 0; m < 2; ++m) {
      int r = rowbase + m * 16 + lr;
      if (r < N_NODES) {
#pragma unroll
        for (int n = 0; n < 4; ++n) {
          int c = (col0 - 256) + n * 16 + lkq * 4;
          float4 br = *(const float4*)&b_res[c];
          ushort4 pk4;
          pk4.x = f2bf(acc[n][m][0] + br.x); pk4.y = f2bf(acc[n][m][1] + br.y);
          pk4.z = f2bf(acc[n][m][2] + br.z); pk4.w = f2bf(acc[n][m][3] + br.w);
          *(ushort4*)&resb[(size_t)r * 256 + c] = pk4;
        }
      }
    }
  }

  // cross-wave hl/hr combine via LDS (reuse As after barrier)
  float* PL = (float*)As;           // [4 waves][32 r][4 h]
  float* PR = PL + 512;
  __syncthreads();
  if (col0 < 256 && lkq == 0) {
#pragma unroll
    for (int m = 0; m < 2; ++m)
#pragma unroll
      for (int h = 0; h < 4; ++h) {
        PL[(wave * 32 + m * 16 + lr) * 4 + h] = pl[m][h];
        PR[(wave * 32 + m * 16 + lr) * 4 + h] = pr[m][h];
      }
  }
  __syncthreads();
  if (tid < 64) {
    int rl = tid >> 1, sel = tid & 1;
    const float* P = sel ? PR : PL;
    float4 v;
    v.x = P[rl * 4 + 0] + P[128 + rl * 4 + 0] + P[256 + rl * 4 + 0] + P[384 + rl * 4 + 0];
    v.y = P[rl * 4 + 1] + P[128 + rl * 4 + 1] + P[256 + rl * 4 + 1] + P[384 + rl * 4 + 1];
    v.z = P[rl * 4 + 2] + P[128 + rl * 4 + 2] + P[256 + rl * 4 + 2] + P[384 + rl * 4 + 2];
    v.w = P[rl * 4 + 3] + P[128 + rl * 4 + 3] + P[256 + rl * 4 + 3] + P[384 + rl * 4 + 3];
    int r = rowbase + rl;
    if (r < N_NODES) *(float4*)&(sel ? hr : hl)[r * 4] = v;
  }
}

// ---------------- agg: phase A computes attention into LDS, phase B aggregates ----
__global__ __launch_bounds__(256) void agg_kernel(
    const int* __restrict__ cnt, const uint2* __restrict__ slots,
    const float* __restrict__ hl, const float* __restrict__ hr,
    const float* __restrict__ he_type,
    const ushort* __restrict__ emb_t, const ushort* __restrict__ resb,
    float* __restrict__ out) {
  __shared__ uint4 meta[4 * CAP];   // {att01, att23, src, 0} per edge, 6 KB
  const int wv = threadIdx.x >> 6;
  const int lane = threadIdx.x & 63;
  const int nu = __builtin_amdgcn_readfirstlane(blockIdx.x * 4 + wv);
  const int cn = min(cnt[nu], CAP);

  // ---- phase A: attention for this wave's node ----
  {
    float4 R = *(const float4*)&hr[nu * 4];
    for (int j = lane; j < cn; j += 64) {
      uint2 s = slots[(size_t)nu * CAP + j];
      int src = s.x & 0xffff, t = s.x >> 16;
      float w = __uint_as_float(s.y);
      float4 L = *(const float4*)&hl[src * 4];
      float4 He = *(const float4*)&he_type[t * 4];
      float x[4] = {L.x + R.x + He.x, L.y + R.y + He.y,
                    L.z + R.z + He.z, L.w + R.w + He.w};
      float a[4];
#pragma unroll
      for (int h = 0; h < 4; ++h) {
        float v = x[h];
        v = v >= 0.f ? v : SLOPE * v;
        a[h] = w / (1.f + __expf(-v));
      }
      uint4 m;
      m.x = pk2(a[0], a[1]);
      m.y = pk2(a[2], a[3]);
      m.z = (unsigned)src;
      m.w = 0;
      meta[wv * CAP + j] = m;
    }
  }
  __syncthreads();

  // ---- phase B: gather-aggregate ----
  float acc0 = 0.f, acc1 = 0.f, acc2 = 0.f, acc3 = 0.f;
  const uint4* mb = &meta[wv * CAP];

#define AGG_FMA(V, WA, WB)                                      \
  acc0 = fmaf(bf2f((V).x), __uint_as_float((WA) << 16), acc0);  \
  acc1 = fmaf(bf2f((V).y), __uint_as_float((WA) & 0xffff0000u), acc1); \
  acc2 = fmaf(bf2f((V).z), __uint_as_float((WB) << 16), acc2);  \
  acc3 = fmaf(bf2f((V).w), __uint_as_float((WB) & 0xffff0000u), acc3);

  const int j4 = cn & ~3;
#pragma unroll 2
  for (int j = 0; j < j4; j += 4) {
    uint4 m0 = mb[j], m1 = mb[j + 1], m2 = mb[j + 2], m3 = mb[j + 3];
    ushort4 v0 = *(const ushort4*)&emb_t[((size_t)m0.z * 64 + lane) * 4];
    ushort4 v1 = *(const ushort4*)&emb_t[((size_t)m1.z * 64 + lane) * 4];
    ushort4 v2 = *(const ushort4*)&emb_t[((size_t)m2.z * 64 + lane) * 4];
    ushort4 v3 = *(const ushort4*)&emb_t[((size_t)m3.z * 64 + lane) * 4];
    AGG_FMA(v0, m0.x, m0.y)
    AGG_FMA(v1, m1.x, m1.y)
    AGG_FMA(v2, m2.x, m2.y)
    AGG_FMA(v3, m3.x, m3.y)
  }
  for (int j = j4; j < cn; ++j) {
    uint4 m0 = mb[j];
    ushort4 v0 = *(const ushort4*)&emb_t[((size_t)m0.z * 64 + lane) * 4];
    AGG_FMA(v0, m0.x, m0.y)
  }
#undef AGG_FMA

  ushort4 r4 = *(const ushort4*)&resb[((size_t)nu * 64 + lane) * 4];
  float v0 = acc0 + bf2f(r4.x), v1 = acc1 + bf2f(r4.y);
  float v2 = acc2 + bf2f(r4.z), v3 = acc3 + bf2f(r4.w);
  float4 o;
  o.x = v0 > 0.f ? v0 : expm1f(v0);
  o.y = v1 > 0.f ? v1 : expm1f(v1);
  o.z = v2 > 0.f ? v2 : expm1f(v2);
  o.w = v3 > 0.f ? v3 : expm1f(v3);
  *(float4*)&out[((size_t)nu * 64 + lane) * 4] = o;
}

extern "C" void kernel_launch(void* const* d_in, const int* in_sizes, int n_in,
                              void* d_out, int out_size, void* d_ws, size_t ws_size,
                              hipStream_t stream) {
  const float* feat = (const float*)d_in[0];
  const float* ew = (const float*)d_in[1];
  const int* row = (const int*)d_in[2];
  const int* col = (const int*)d_in[3];
  const int* etype = (const int*)d_in[4];
  const float* W = (const float*)d_in[5];
  const float* table = (const float*)d_in[6];
  const float* W_r = (const float*)d_in[7];
  const float* a_l = (const float*)d_in[8];
  const float* a_r = (const float*)d_in[9];
  const float* a_e = (const float*)d_in[10];
  const float* W_res = (const float*)d_in[11];
  const float* b_res = (const float*)d_in[12];
  float* out = (float*)d_out;

  char* w = (char*)d_ws;
  auto alloc = [&](size_t bytes) {
    char* pp = w;
    w += (bytes + 255) & ~(size_t)255;
    return pp;
  };
  ushort* Wtb = (ushort*)alloc((size_t)512 * 256 * 2);
  ushort* emb_t = (ushort*)alloc((size_t)N_NODES * 256 * 2);  // [n][d][h] bf16
  ushort* resb = (ushort*)alloc((size_t)N_NODES * 256 * 2);   // [n][d*4+h] bf16
  uint2* slots = (uint2*)alloc((size_t)N_NODES * CAP * 8);    // {et<<16|src, ew}
  float* hl = (float*)alloc((size_t)N_NODES * NH * 4);
  float* hr = (float*)alloc((size_t)N_NODES * NH * 4);
  float* he_type = (float*)alloc(NT * NH * 4);
  int* cnt = (int*)alloc((size_t)(N_NODES + 1) * 4);

  const int PREP_BLOCKS = WTW / 256 + 4 + (N_NODES + 256) / 256;  // 512 + 4 + 40
  prep_kernel<<<PREP_BLOCKS, 256, 0, stream>>>(W, W_res, table, W_r, a_e,
                                               Wtb, he_type, cnt);
  gemm_bucket_kernel<<<GB + EB, 512, 0, stream>>>(
      feat, Wtb, b_res, a_l, a_r, emb_t, resb, hl, hr,
      row, col, etype, ew, cnt, slots);
  agg_kernel<<<N_NODES / 4, 256, 0, stream>>>(cnt, slots, hl, hr, he_type,
                                              emb_t, resb, out);
}